// Round 16
// baseline (42.036 us; speedup 1.0000x reference)
//
#include <hip/hip_runtime.h>

#define BB 8
#define CC 384
#define HH 64
#define WW 64
#define NH 6
#define HD 64
#define PLANE (HH*WW)        /* 4096 */
#define QKSCALE 0.125f
#define CH_B  (PLANE*4)      /* 16384 bytes per channel step */

typedef float f32x4 __attribute__((ext_vector_type(4)));
typedef int   i32x4 __attribute__((ext_vector_type(4)));

__device__ __forceinline__ i32x4 make_srsrc(const void* p) {
  union { unsigned long long a; int w[2]; } u; u.a = (unsigned long long)p;
  i32x4 r; r.x = u.w[0]; r.y = u.w[1]; r.z = -1 /*num_records: disable*/; r.w = 0x00020000;
  return r;
}

// buffer_load_dwordx4: 16B per lane; counted by vmcnt, issue order pinned by volatile.
__device__ __forceinline__ void blx4(f32x4& dst, i32x4 rsrc, int voff, int soff) {
  asm volatile("buffer_load_dwordx4 %0, %1, %2, %3 offen"
               : "=v"(dst) : "v"(voff), "s"(rsrc), "s"(soff));
}

__global__ __launch_bounds__(256, 3) void dilate_attn_kernel(
    const float* __restrict__ qg, const float* __restrict__ kg,
    const float* __restrict__ vg, float* __restrict__ outg) {
  // bijective XCD swizzle: 768 blocks, 96 per XCD
  const int blk  = (blockIdx.x % 8) * 96 + (blockIdx.x / 8);
  const int y0   = (blk % 16) * 4;
  const int bh   = blk / 16;           // b*NH + head
  const int head = bh % NH;
  const int b    = bh / NH;
  const int lane = threadIdx.x & 63;
  const int warp = threadIdx.x >> 6;
  const int y = y0 + warp;
  const int g = lane >> 4;             // channel subgroup 0..3
  const int u = lane & 15;             // x-quad index: pixels 4u..4u+3

  const int laneM = (lane & 48) | ((u + 15) & 15);  // quad u-1 (halo x-1)
  const int laneP = (lane & 48) | ((u + 1) & 15);   // quad u+1 (halo x+4)

  const i32x4 rq = make_srsrc(qg);
  const i32x4 rk = make_srsrc(kg);
  const i32x4 rv = make_srsrc(vg);

  // per-lane byte base: head slab + this lane's channel-subgroup + pixel quad
  const int slab4 = (b * CC + head * HD) * (PLANE * 4) + g * CH_B;
  const int voq = slab4 + (y * WW + 4 * u) * 4;

  int vok[3]; float rowm[3];
#pragma unroll
  for (int r = 0; r < 3; ++r) {
    const int yy = y + r - 1;
    const int yc = min(max(yy, 0), HH - 1);
    vok[r] = slab4 + (yc * WW + 4 * u) * 4;
    rowm[r] = (yy >= 0 && yy < HH) ? 1.0f : 0.0f;
  }
  const float eL = (u == 0)  ? 0.0f : 1.0f;   // x=0 lacks x-1 tap
  const float eR = (u == 15) ? 0.0f : 1.0f;   // x=63 lacks x+1 tap

  // ---- QK^T: t[r*3+(dx+1)][j] = sum_d q_d(x_j) * k_d(row r, x_j+dx) ----
  // Depth-3 pipeline: chunk c's 8 loads issued at iteration c-2 (cover ~2 iters).
  float t[9][4];
#pragma unroll
  for (int i = 0; i < 9; ++i)
#pragma unroll
    for (int j = 0; j < 4; ++j) t[i][j] = 0.0f;

  f32x4 qb[3][2], kb[3][6];
#pragma unroll
  for (int pc = 0; pc < 2; ++pc) {     // prologue: chunks 0,1 (16 loads out)
    const int cb = pc * 8;
    blx4(qb[pc][0], rq, voq, (cb + 0) * CH_B);
    blx4(qb[pc][1], rq, voq, (cb + 4) * CH_B);
#pragma unroll
    for (int r = 0; r < 3; ++r)
#pragma unroll
      for (int ci = 0; ci < 2; ++ci)
        blx4(kb[pc][r * 2 + ci], rk, vok[r], (cb + 4 * ci) * CH_B);
  }

#pragma unroll
  for (int c = 0; c < 8; ++c) {
    const int cur = c % 3;
    if (c < 6) {
      const int nb = (c + 2) % 3;
      const int cb = (c + 2) * 8;
      blx4(qb[nb][0], rq, voq, (cb + 0) * CH_B);
      blx4(qb[nb][1], rq, voq, (cb + 4) * CH_B);
#pragma unroll
      for (int r = 0; r < 3; ++r)
#pragma unroll
        for (int ci = 0; ci < 2; ++ci)
          blx4(kb[nb][r * 2 + ci], rk, vok[r], (cb + 4 * ci) * CH_B);
    }
    // chunk c ready: newer LOADS = chunks c+1,c+2 (loads-only suffix -> safe)
    if (c < 6)      { asm volatile("s_waitcnt vmcnt(16)" ::: "memory"); }
    else if (c == 6){ asm volatile("s_waitcnt vmcnt(8)"  ::: "memory"); }
    else            { asm volatile("s_waitcnt vmcnt(0)"  ::: "memory"); }
    __builtin_amdgcn_sched_barrier(0);

#pragma unroll
    for (int ci = 0; ci < 2; ++ci) {
      const f32x4 qv = qb[cur][ci];
#pragma unroll
      for (int r = 0; r < 3; ++r) {
        const f32x4 kv = kb[cur][r * 2 + ci];
        const float km1 = __shfl(kv[3], laneM);   // k(x-1 of quad)
        const float kp4 = __shfl(kv[0], laneP);   // k(x+4 of quad)
        // dx=-1: k at x_j-1
        t[r*3+0][0] = fmaf(qv[0], km1,  t[r*3+0][0]);
        t[r*3+0][1] = fmaf(qv[1], kv[0], t[r*3+0][1]);
        t[r*3+0][2] = fmaf(qv[2], kv[1], t[r*3+0][2]);
        t[r*3+0][3] = fmaf(qv[3], kv[2], t[r*3+0][3]);
        // dx=0
        t[r*3+1][0] = fmaf(qv[0], kv[0], t[r*3+1][0]);
        t[r*3+1][1] = fmaf(qv[1], kv[1], t[r*3+1][1]);
        t[r*3+1][2] = fmaf(qv[2], kv[2], t[r*3+1][2]);
        t[r*3+1][3] = fmaf(qv[3], kv[3], t[r*3+1][3]);
        // dx=+1: k at x_j+1
        t[r*3+2][0] = fmaf(qv[0], kv[1], t[r*3+2][0]);
        t[r*3+2][1] = fmaf(qv[1], kv[2], t[r*3+2][1]);
        t[r*3+2][2] = fmaf(qv[2], kv[3], t[r*3+2][2]);
        t[r*3+2][3] = fmaf(qv[3], kp4,  t[r*3+2][3]);
      }
    }
  }

  // ---- issue PV chunks 0,1: fly under the reduce + softmax ----
  f32x4 vb[3][6];
#pragma unroll
  for (int pc = 0; pc < 2; ++pc) {
    const int cb = pc * 8;
#pragma unroll
    for (int r = 0; r < 3; ++r)
#pragma unroll
      for (int ci = 0; ci < 2; ++ci)
        blx4(vb[pc][r * 2 + ci], rv, vok[r], (cb + 4 * ci) * CH_B);
  }

  // ---- butterfly reduce over channel subgroups (g): xor 16, xor 32 ----
#pragma unroll
  for (int i = 0; i < 9; ++i)
#pragma unroll
    for (int j = 0; j < 4; ++j) {
      t[i][j] += __shfl_xor(t[i][j], 16);
      t[i][j] += __shfl_xor(t[i][j], 32);
    }

  // ---- softmax per pixel j (masked entries exactly 0, matching zero-pad ref) ----
  float p[9][4];
#pragma unroll
  for (int j = 0; j < 4; ++j) {
    float sj[9];
#pragma unroll
    for (int r = 0; r < 3; ++r)
#pragma unroll
      for (int d = 0; d < 3; ++d)
        sj[r * 3 + d] = t[r * 3 + d][j] * rowm[r] * QKSCALE;
    if (j == 0) { sj[0] *= eL; sj[3] *= eL; sj[6] *= eL; }
    if (j == 3) { sj[2] *= eR; sj[5] *= eR; sj[8] *= eR; }
    float mx = sj[0];
#pragma unroll
    for (int i = 1; i < 9; ++i) mx = fmaxf(mx, sj[i]);
    float sum = 0.0f;
#pragma unroll
    for (int i = 0; i < 9; ++i) { sj[i] = __expf(sj[i] - mx); sum += sj[i]; }
    const float inv = 1.0f / sum;
#pragma unroll
    for (int r = 0; r < 3; ++r)
#pragma unroll
      for (int d = 0; d < 3; ++d)
        p[r * 3 + d][j] = sj[r * 3 + d] * inv * rowm[r];  // fold row mask into p
    if (j == 0) { p[0][0] *= eL; p[3][0] *= eL; p[6][0] *= eL; }
    if (j == 3) { p[2][3] *= eR; p[5][3] *= eR; p[8][3] *= eR; }
  }

  // ---- PV + per-wave LDS transpose (64x9 pad: 2-way banks = free) ----
  __shared__ float ldsT[4][576];
  float* ldsw = ldsT[warp];
  float* outp = outg + ((long)((b * HH + y) * WW + lane)) * CC + head * HD;

#pragma unroll
  for (int c = 0; c < 8; ++c) {
    const int cur = c % 3;
    if (c < 6) {
      const int nb = (c + 2) % 3;
      const int cb = (c + 2) * 8;
#pragma unroll
      for (int r = 0; r < 3; ++r)
#pragma unroll
        for (int ci = 0; ci < 2; ++ci)
          blx4(vb[nb][r * 2 + ci], rv, vok[r], (cb + 4 * ci) * CH_B);
    }
    // v(c) ready: newer LOADS = chunks c+1,c+2 = 12 (compiler stores only
    // lengthen the wait -> safe)
    if (c < 6)      { asm volatile("s_waitcnt vmcnt(12)" ::: "memory"); }
    else if (c == 6){ asm volatile("s_waitcnt vmcnt(6)"  ::: "memory"); }
    else            { asm volatile("s_waitcnt vmcnt(0)"  ::: "memory"); }
    __builtin_amdgcn_sched_barrier(0);

    float o[2][4];
#pragma unroll
    for (int ci = 0; ci < 2; ++ci)
#pragma unroll
      for (int j = 0; j < 4; ++j) o[ci][j] = 0.0f;

#pragma unroll
    for (int ci = 0; ci < 2; ++ci)
#pragma unroll
      for (int r = 0; r < 3; ++r) {
        const f32x4 vv = vb[cur][r * 2 + ci];
        const float vm1 = __shfl(vv[3], laneM);
        const float vp4 = __shfl(vv[0], laneP);
        o[ci][0] += p[r*3+0][0]*vm1  + p[r*3+1][0]*vv[0] + p[r*3+2][0]*vv[1];
        o[ci][1] += p[r*3+0][1]*vv[0] + p[r*3+1][1]*vv[1] + p[r*3+2][1]*vv[2];
        o[ci][2] += p[r*3+0][2]*vv[1] + p[r*3+1][2]*vv[2] + p[r*3+2][2]*vv[3];
        o[ci][3] += p[r*3+0][3]*vv[2] + p[r*3+1][3]*vv[3] + p[r*3+2][3]*vp4;
      }

    // transpose (g,u)-layout -> pixel layout through LDS (same-wave, in-order DS)
#pragma unroll
    for (int ci = 0; ci < 2; ++ci)
#pragma unroll
      for (int j = 0; j < 4; ++j)
        ldsw[(4 * u + j) * 9 + 4 * ci + g] = o[ci][j];

    f32x4 o0, o1;
#pragma unroll
    for (int c2 = 0; c2 < 4; ++c2) {
      o0[c2] = ldsw[lane * 9 + c2];
      o1[c2] = ldsw[lane * 9 + 4 + c2];
    }
    *reinterpret_cast<f32x4*>(outp + c * 8)     = o0;
    *reinterpret_cast<f32x4*>(outp + c * 8 + 4) = o1;
  }
}

extern "C" void kernel_launch(void* const* d_in, const int* in_sizes, int n_in,
                              void* d_out, int out_size, void* d_ws, size_t ws_size,
                              hipStream_t stream) {
  const float* q = (const float*)d_in[0];
  const float* k = (const float*)d_in[1];
  const float* v = (const float*)d_in[2];
  float* out = (float*)d_out;
  const int blocks = BB * NH * (HH / 4);  // 768
  dilate_attn_kernel<<<blocks, 256, 0, stream>>>(q, k, v, out);
}